// Round 1
// baseline (611.947 us; speedup 1.0000x reference)
//
#include <hip/hip_runtime.h>
#include <math.h>

#define N 8192
#define IN_DIM 128
#define HID 32

#define RB 128          // rows per spmm block
#define KT 64           // k-tile
#define SK 8            // split-K factor
#define KCHUNK (N / SK) // 1024

__device__ __forceinline__ void fma4(float4& acc, float a, const float4& b) {
    acc.x = fmaf(a, b.x, acc.x);
    acc.y = fmaf(a, b.y, acc.y);
    acc.z = fmaf(a, b.z, acc.z);
    acc.w = fmaf(a, b.w, acc.w);
}

// degree[i] = 1 + sum_j adj[i][j];  dinv[i] = 1/sqrt(max(degree,1))
__global__ __launch_bounds__(256) void k_degree(const float* __restrict__ adj,
                                                float* __restrict__ dinv) {
    int row = blockIdx.x;
    const float4* rp = (const float4*)(adj + (size_t)row * N);
    int t = threadIdx.x;
    float s = 0.f;
#pragma unroll
    for (int i = 0; i < 8; ++i) {
        float4 v = rp[t + i * 256];
        s += v.x + v.y + v.z + v.w;
    }
    for (int off = 32; off > 0; off >>= 1) s += __shfl_down(s, off, 64);
    __shared__ float red[4];
    if ((t & 63) == 0) red[t >> 6] = s;
    __syncthreads();
    if (t == 0) {
        float deg = red[0] + red[1] + red[2] + red[3] + 1.0f;  // +1 self loop
        deg = fmaxf(deg, 1.0f);
        dinv[row] = 1.0f / sqrtf(deg);
    }
}

// Zs[i][c] = dinv[i] * (x[i] @ W1 + b1)[c]   (x: [N,128], W1: [128,32])
__global__ __launch_bounds__(256) void k_z1(const float* __restrict__ x,
                                            const float* __restrict__ W1,
                                            const float* __restrict__ b1,
                                            const float* __restrict__ dinv,
                                            float* __restrict__ Zs) {
    __shared__ float Ws[IN_DIM * HID];  // 4096 floats
    __shared__ float xs[8 * IN_DIM];    // 1024 floats
    int t = threadIdx.x;
    int row0 = blockIdx.x * 8;
#pragma unroll
    for (int i = 0; i < 4; ++i)
        *(float4*)&Ws[(i * 256 + t) * 4] = *(const float4*)&W1[(i * 256 + t) * 4];
    *(float4*)&xs[t * 4] = *(const float4*)&x[(size_t)row0 * IN_DIM + t * 4];
    __syncthreads();
    int r = t >> 5, c = t & 31;
    float acc = b1[c];
#pragma unroll 8
    for (int k = 0; k < IN_DIM; ++k) acc = fmaf(xs[r * IN_DIM + k], Ws[k * HID + c], acc);
    int row = row0 + r;
    Zs[(size_t)row * HID + c] = dinv[row] * acc;
}

// Zs[i][c] = dinv[i] * (Hin[i] @ W2 + b2)[c]   (Hin: [N,32], W2: [32,32])
__global__ __launch_bounds__(256) void k_z2(const float* __restrict__ Hin,
                                            const float* __restrict__ W2,
                                            const float* __restrict__ b2,
                                            const float* __restrict__ dinv,
                                            float* __restrict__ Zs) {
    __shared__ float Ws[HID * HID];  // 1024 floats
    __shared__ float hs[8 * HID];    // 256 floats
    int t = threadIdx.x;
    int row0 = blockIdx.x * 8;
    *(float4*)&Ws[t * 4] = *(const float4*)&W2[t * 4];
    if (t < 64) *(float4*)&hs[t * 4] = *(const float4*)&Hin[(size_t)row0 * HID + t * 4];
    __syncthreads();
    int r = t >> 5, c = t & 31;
    float acc = b2[c];
#pragma unroll
    for (int k = 0; k < HID; ++k) acc = fmaf(hs[r * HID + k], Ws[k * HID + c], acc);
    int row = row0 + r;
    Zs[(size_t)row * HID + c] = dinv[row] * acc;
}

// P += adj[rows, kchunk] @ Zs[kchunk, 32]  (atomic split-K accumulate)
__global__ __launch_bounds__(256) void k_spmm(const float* __restrict__ adj,
                                              const float* __restrict__ Zs,
                                              float* __restrict__ P) {
    __shared__ float As[RB][KT + 4];  // pad 4: keeps 16B alignment, spreads banks
    __shared__ float Bs[KT][HID];
    int t = threadIdx.x;
    int r0 = blockIdx.x * RB;
    int k0 = blockIdx.y * KCHUNK;
    int cg = t & 3;           // 4 col groups of 8
    int rp2 = (t >> 2) * 2;   // row pair base 0..126
    float4 acc00 = {0, 0, 0, 0}, acc01 = {0, 0, 0, 0};
    float4 acc10 = {0, 0, 0, 0}, acc11 = {0, 0, 0, 0};

    for (int kt = k0; kt < k0 + KCHUNK; kt += KT) {
        // stage A tile: 128 rows x 64 k, 8 float4 per thread, coalesced rows
#pragma unroll
        for (int i = 0; i < 8; ++i) {
            int f = i * 256 + t;         // float4 index in tile
            int row = f >> 4;            // 16 float4 per row
            int kc = (f & 15) << 2;
            *(float4*)&As[row][kc] = *(const float4*)&adj[(size_t)(r0 + row) * N + kt + kc];
        }
        // stage B tile: 64 x 32 floats, fully contiguous in global
#pragma unroll
        for (int i = 0; i < 2; ++i) {
            int f = i * 256 + t;
            ((float4*)&Bs[0][0])[f] = ((const float4*)(Zs + (size_t)kt * HID))[f];
        }
        __syncthreads();
#pragma unroll
        for (int kk = 0; kk < KT; kk += 4) {
            float a0[4], a1[4];
            *(float4*)a0 = *(const float4*)&As[rp2][kk];
            *(float4*)a1 = *(const float4*)&As[rp2 + 1][kk];
#pragma unroll
            for (int j = 0; j < 4; ++j) {
                float4 z0 = *(const float4*)&Bs[kk + j][cg * 8];
                float4 z1 = *(const float4*)&Bs[kk + j][cg * 8 + 4];
                fma4(acc00, a0[j], z0);
                fma4(acc01, a0[j], z1);
                fma4(acc10, a1[j], z0);
                fma4(acc11, a1[j], z1);
            }
        }
        __syncthreads();
    }

    float* p0 = P + (size_t)(r0 + rp2) * HID + cg * 8;
    float* p1 = p0 + HID;
    atomicAdd(p0 + 0, acc00.x); atomicAdd(p0 + 1, acc00.y);
    atomicAdd(p0 + 2, acc00.z); atomicAdd(p0 + 3, acc00.w);
    atomicAdd(p0 + 4, acc01.x); atomicAdd(p0 + 5, acc01.y);
    atomicAdd(p0 + 6, acc01.z); atomicAdd(p0 + 7, acc01.w);
    atomicAdd(p1 + 0, acc10.x); atomicAdd(p1 + 1, acc10.y);
    atomicAdd(p1 + 2, acc10.z); atomicAdd(p1 + 3, acc10.w);
    atomicAdd(p1 + 4, acc11.x); atomicAdd(p1 + 5, acc11.y);
    atomicAdd(p1 + 6, acc11.z); atomicAdd(p1 + 7, acc11.w);
}

// H[i][c] = relu(dinv[i] * (P[i][c] + Zs[i][c]))   (Zs term = self loop)
__global__ __launch_bounds__(256) void k_fin(const float* __restrict__ P,
                                             const float* __restrict__ Zs,
                                             const float* __restrict__ dinv,
                                             float* __restrict__ H) {
    int idx = blockIdx.x * 256 + threadIdx.x;
    int row = idx >> 5;
    float v = dinv[row] * (P[idx] + Zs[idx]);
    H[idx] = fmaxf(v, 0.f);
}

// out[i] = H[i] @ W3 + b3
__global__ __launch_bounds__(256) void k_out(const float* __restrict__ H,
                                             const float* __restrict__ W3,
                                             const float* __restrict__ b3,
                                             float* __restrict__ out) {
    int i = blockIdx.x * 256 + threadIdx.x;
    const float4* hr = (const float4*)(H + (size_t)i * HID);
    const float4* w = (const float4*)W3;
    float acc = b3[0];
#pragma unroll
    for (int kk = 0; kk < 8; ++kk) {
        float4 h = hr[kk], ww = w[kk];
        acc += h.x * ww.x + h.y * ww.y + h.z * ww.z + h.w * ww.w;
    }
    out[i] = acc;
}

extern "C" void kernel_launch(void* const* d_in, const int* in_sizes, int n_in,
                              void* d_out, int out_size, void* d_ws, size_t ws_size,
                              hipStream_t stream) {
    const float* x   = (const float*)d_in[0];
    const float* adj = (const float*)d_in[1];
    const float* W1  = (const float*)d_in[2];
    const float* b1  = (const float*)d_in[3];
    const float* W2  = (const float*)d_in[4];
    const float* b2  = (const float*)d_in[5];
    const float* W3  = (const float*)d_in[6];
    const float* b3  = (const float*)d_in[7];
    float* out = (float*)d_out;

    float* dinv = (float*)d_ws;               // 8192 floats
    float* Zs   = dinv + N;                   // N*32 floats (1 MB)
    float* P    = Zs + (size_t)N * HID;       // N*32 floats (1 MB)
    float* H    = P + (size_t)N * HID;        // N*32 floats (1 MB)

    k_degree<<<N, 256, 0, stream>>>(adj, dinv);
    k_z1<<<N / 8, 256, 0, stream>>>(x, W1, b1, dinv, Zs);

    hipMemsetAsync(P, 0, (size_t)N * HID * sizeof(float), stream);
    k_spmm<<<dim3(N / RB, SK), 256, 0, stream>>>(adj, Zs, P);
    k_fin<<<N * HID / 256, 256, 0, stream>>>(P, Zs, dinv, H);

    k_z2<<<N / 8, 256, 0, stream>>>(H, W2, b2, dinv, Zs);

    hipMemsetAsync(P, 0, (size_t)N * HID * sizeof(float), stream);
    k_spmm<<<dim3(N / RB, SK), 256, 0, stream>>>(adj, Zs, P);
    k_fin<<<N * HID / 256, 256, 0, stream>>>(P, Zs, dinv, H);

    k_out<<<N / 256, 256, 0, stream>>>(H, W3, b3, out);
}